// Round 2
// baseline (6115.686 us; speedup 1.0000x reference)
//
#include <hip/hip_runtime.h>
#include <cstddef>

#define CCH 256   // channels
#define EPB 16    // edges/nodes per block
#define KCH 32    // K-chunk rows staged in LDS
#define TPB 256   // threads per block

// ---------------------------------------------------------------------------
// Edge kernel: per edge e with src s, dst d:
//   h1   = relu(x_dst[d] @ W1 + b1)
//   pred = h1 @ W2 + b2
//   res  = x_src[s] - pred
//   msg  = LN(res) * mg + mb
//   atomic: agg[d] += msg ; cnt[d] += 1
// Block handles 16 edges; each wave owns 4 edges x all 256 cols
// (lane holds 4 cols), so LayerNorm reduction is a single-wave shfl reduce.
// ---------------------------------------------------------------------------
__global__ __launch_bounds__(TPB)
void edge_conv_kernel(const float* __restrict__ x_src,
                      const float* __restrict__ x_dst,
                      const int* __restrict__ ei, int E,
                      const float* __restrict__ pw1, const float* __restrict__ pb1,
                      const float* __restrict__ pw2, const float* __restrict__ pb2,
                      const float* __restrict__ mg, const float* __restrict__ mb,
                      float* __restrict__ agg, float* __restrict__ cnt)
{
    __shared__ __align__(16) float xdT[CCH][EPB + 4];  // [k][e] transposed dst feats
    __shared__ __align__(16) float h1T[CCH][EPB + 4];  // [k][e] hidden
    __shared__ __align__(16) float wt[KCH][CCH];       // weight chunk
    __shared__ int s_src[EPB];
    __shared__ int s_dst[EPB];

    const int tid  = threadIdx.x;
    const int lane = tid & 63;
    const int wv   = tid >> 6;
    const int eg   = wv * 4;       // this wave's 4 edges
    const int cg   = lane * 4;     // this lane's 4 columns
    const int e0   = blockIdx.x * EPB;

    if (tid < EPB) {
        int e  = e0 + tid;
        int se = (e < E) ? e : (E - 1);
        s_src[tid] = ei[se];         // row 0 = src
        s_dst[tid] = ei[E + se];     // row 1 = dst
    }
    __syncthreads();

    // gather dst rows (coalesced: thread = channel), store transposed
    #pragma unroll
    for (int e = 0; e < EPB; ++e)
        xdT[tid][e] = x_dst[(size_t)s_dst[e] * CCH + tid];

    float acc[4][4];
    #pragma unroll
    for (int i = 0; i < 4; ++i)
        #pragma unroll
        for (int j = 0; j < 4; ++j) acc[i][j] = 0.f;

    // ---- matmul 1: xd @ W1
    for (int kc = 0; kc < CCH; kc += KCH) {
        __syncthreads();
        const float4* wsrc = (const float4*)(pw1 + (size_t)kc * CCH);
        float4* wdst = (float4*)&wt[0][0];
        #pragma unroll
        for (int i = 0; i < (KCH * CCH / 4) / TPB; ++i)
            wdst[tid + i * TPB] = wsrc[tid + i * TPB];
        __syncthreads();
        #pragma unroll 8
        for (int k = 0; k < KCH; ++k) {
            const float4 a = *(const float4*)&xdT[kc + k][eg];
            const float4 w = *(const float4*)&wt[k][cg];
            acc[0][0] += a.x*w.x; acc[0][1] += a.x*w.y; acc[0][2] += a.x*w.z; acc[0][3] += a.x*w.w;
            acc[1][0] += a.y*w.x; acc[1][1] += a.y*w.y; acc[1][2] += a.y*w.z; acc[1][3] += a.y*w.w;
            acc[2][0] += a.z*w.x; acc[2][1] += a.z*w.y; acc[2][2] += a.z*w.z; acc[2][3] += a.z*w.w;
            acc[3][0] += a.w*w.x; acc[3][1] += a.w*w.y; acc[3][2] += a.w*w.z; acc[3][3] += a.w*w.w;
        }
    }

    // bias + relu -> h1T (transposed)
    #pragma unroll
    for (int j = 0; j < 4; ++j) {
        const float b = pb1[cg + j];
        float4 v;
        v.x = fmaxf(acc[0][j] + b, 0.f);
        v.y = fmaxf(acc[1][j] + b, 0.f);
        v.z = fmaxf(acc[2][j] + b, 0.f);
        v.w = fmaxf(acc[3][j] + b, 0.f);
        *(float4*)&h1T[cg + j][eg] = v;
    }

    #pragma unroll
    for (int i = 0; i < 4; ++i)
        #pragma unroll
        for (int j = 0; j < 4; ++j) acc[i][j] = 0.f;

    // ---- matmul 2: h1 @ W2   (first __syncthreads also fences h1T writes)
    for (int kc = 0; kc < CCH; kc += KCH) {
        __syncthreads();
        const float4* wsrc = (const float4*)(pw2 + (size_t)kc * CCH);
        float4* wdst = (float4*)&wt[0][0];
        #pragma unroll
        for (int i = 0; i < (KCH * CCH / 4) / TPB; ++i)
            wdst[tid + i * TPB] = wsrc[tid + i * TPB];
        __syncthreads();
        #pragma unroll 8
        for (int k = 0; k < KCH; ++k) {
            const float4 a = *(const float4*)&h1T[kc + k][eg];
            const float4 w = *(const float4*)&wt[k][cg];
            acc[0][0] += a.x*w.x; acc[0][1] += a.x*w.y; acc[0][2] += a.x*w.z; acc[0][3] += a.x*w.w;
            acc[1][0] += a.y*w.x; acc[1][1] += a.y*w.y; acc[1][2] += a.y*w.z; acc[1][3] += a.y*w.w;
            acc[2][0] += a.z*w.x; acc[2][1] += a.z*w.y; acc[2][2] += a.z*w.z; acc[2][3] += a.z*w.w;
            acc[3][0] += a.w*w.x; acc[3][1] += a.w*w.y; acc[3][2] += a.w*w.z; acc[3][3] += a.w*w.w;
        }
    }

    // residual + LayerNorm + atomic aggregation
    float pb2v[4], mgv[4], mbv[4];
    #pragma unroll
    for (int j = 0; j < 4; ++j) {
        pb2v[j] = pb2[cg + j];
        mgv[j]  = mg[cg + j];
        mbv[j]  = mb[cg + j];
    }

    #pragma unroll
    for (int i = 0; i < 4; ++i) {
        const int er = eg + i;
        const float4 xs = *(const float4*)&x_src[(size_t)s_src[er] * CCH + cg];
        const float r0 = xs.x - (acc[i][0] + pb2v[0]);
        const float r1 = xs.y - (acc[i][1] + pb2v[1]);
        const float r2 = xs.z - (acc[i][2] + pb2v[2]);
        const float r3 = xs.w - (acc[i][3] + pb2v[3]);
        float s = r0 + r1 + r2 + r3;
        float q = r0*r0 + r1*r1 + r2*r2 + r3*r3;
        #pragma unroll
        for (int m = 32; m >= 1; m >>= 1) {
            s += __shfl_xor(s, m);
            q += __shfl_xor(q, m);
        }
        const float mu   = s * (1.f / CCH);
        const float var  = q * (1.f / CCH) - mu * mu;
        const float rstd = rsqrtf(var + 1e-5f);
        if (e0 + er < E) {
            const int dn = s_dst[er];
            float* ap = agg + (size_t)dn * CCH + cg;
            atomicAdd(ap + 0, (r0 - mu) * rstd * mgv[0] + mbv[0]);
            atomicAdd(ap + 1, (r1 - mu) * rstd * mgv[1] + mbv[1]);
            atomicAdd(ap + 2, (r2 - mu) * rstd * mgv[2] + mbv[2]);
            atomicAdd(ap + 3, (r3 - mu) * rstd * mgv[3] + mbv[3]);
            if (lane == 0) atomicAdd(cnt + dn, 1.f);
        }
    }
}

// ---------------------------------------------------------------------------
// Node kernel: out = LN( concat(x, agg/max(cnt,1)) @ LW + lb ) -> relu,
// written in place into x (each block only touches its own 16 rows).
// ---------------------------------------------------------------------------
__global__ __launch_bounds__(TPB)
void node_update_kernel(float* __restrict__ x,
                        const float* __restrict__ agg,
                        const float* __restrict__ cnt,
                        const float* __restrict__ lw, const float* __restrict__ lb,
                        const float* __restrict__ ng, const float* __restrict__ nb,
                        int N)
{
    __shared__ __align__(16) float aT[2 * CCH][EPB + 4];  // [k][n] concat feats
    __shared__ __align__(16) float wt[KCH][CCH];

    const int tid  = threadIdx.x;
    const int lane = tid & 63;
    const int wv   = tid >> 6;
    const int eg   = wv * 4;
    const int cg   = lane * 4;
    const int n0   = blockIdx.x * EPB;

    #pragma unroll
    for (int e = 0; e < EPB; ++e) {
        const int node = (n0 + e < N) ? (n0 + e) : (N - 1);
        const float inv = 1.f / fmaxf(cnt[node], 1.f);
        aT[tid][e]       = x[(size_t)node * CCH + tid];
        aT[CCH + tid][e] = agg[(size_t)node * CCH + tid] * inv;
    }

    float acc[4][4];
    #pragma unroll
    for (int i = 0; i < 4; ++i)
        #pragma unroll
        for (int j = 0; j < 4; ++j) acc[i][j] = 0.f;

    for (int kc = 0; kc < 2 * CCH; kc += KCH) {
        __syncthreads();   // first iteration also fences aT staging
        const float4* wsrc = (const float4*)(lw + (size_t)kc * CCH);
        float4* wdst = (float4*)&wt[0][0];
        #pragma unroll
        for (int i = 0; i < (KCH * CCH / 4) / TPB; ++i)
            wdst[tid + i * TPB] = wsrc[tid + i * TPB];
        __syncthreads();
        #pragma unroll 8
        for (int k = 0; k < KCH; ++k) {
            const float4 a = *(const float4*)&aT[kc + k][eg];
            const float4 w = *(const float4*)&wt[k][cg];
            acc[0][0] += a.x*w.x; acc[0][1] += a.x*w.y; acc[0][2] += a.x*w.z; acc[0][3] += a.x*w.w;
            acc[1][0] += a.y*w.x; acc[1][1] += a.y*w.y; acc[1][2] += a.y*w.z; acc[1][3] += a.y*w.w;
            acc[2][0] += a.z*w.x; acc[2][1] += a.z*w.y; acc[2][2] += a.z*w.z; acc[2][3] += a.z*w.w;
            acc[3][0] += a.w*w.x; acc[3][1] += a.w*w.y; acc[3][2] += a.w*w.z; acc[3][3] += a.w*w.w;
        }
    }

    float lbv[4], ngv[4], nbv[4];
    #pragma unroll
    for (int j = 0; j < 4; ++j) {
        lbv[j] = lb[cg + j];
        ngv[j] = ng[cg + j];
        nbv[j] = nb[cg + j];
    }

    #pragma unroll
    for (int i = 0; i < 4; ++i) {
        const float o0 = acc[i][0] + lbv[0];
        const float o1 = acc[i][1] + lbv[1];
        const float o2 = acc[i][2] + lbv[2];
        const float o3 = acc[i][3] + lbv[3];
        float s = o0 + o1 + o2 + o3;
        float q = o0*o0 + o1*o1 + o2*o2 + o3*o3;
        #pragma unroll
        for (int m = 32; m >= 1; m >>= 1) {
            s += __shfl_xor(s, m);
            q += __shfl_xor(q, m);
        }
        const float mu   = s * (1.f / CCH);
        const float var  = q * (1.f / CCH) - mu * mu;
        const float rstd = rsqrtf(var + 1e-5f);
        const int node = n0 + eg + i;
        if (node < N) {
            float4 y;
            y.x = fmaxf((o0 - mu) * rstd * ngv[0] + nbv[0], 0.f);
            y.y = fmaxf((o1 - mu) * rstd * ngv[1] + nbv[1], 0.f);
            y.z = fmaxf((o2 - mu) * rstd * ngv[2] + nbv[2], 0.f);
            y.w = fmaxf((o3 - mu) * rstd * ngv[3] + nbv[3], 0.f);
            *(float4*)&x[(size_t)node * CCH + cg] = y;
        }
    }
}

extern "C" void kernel_launch(void* const* d_in, const int* in_sizes, int n_in,
                              void* d_out, int out_size, void* d_ws, size_t ws_size,
                              hipStream_t stream)
{
    const float* x_user = (const float*)d_in[0];
    const float* x_item = (const float*)d_in[1];
    const float* pw1    = (const float*)d_in[2];
    const float* pb1    = (const float*)d_in[3];
    const float* pw2    = (const float*)d_in[4];
    const float* pb2    = (const float*)d_in[5];
    const float* msg_g  = (const float*)d_in[6];
    const float* msg_b  = (const float*)d_in[7];
    const float* lin_w  = (const float*)d_in[8];
    const float* lin_b  = (const float*)d_in[9];
    const float* node_g = (const float*)d_in[10];
    const float* node_b = (const float*)d_in[11];
    const int*   ei_ui  = (const int*)d_in[12];
    const int*   ei_iu  = (const int*)d_in[13];

    const int NU = in_sizes[0] / CCH;
    const int NI = in_sizes[1] / CCH;
    const int E0 = in_sizes[12] / 2;
    const int E1 = in_sizes[13] / 2;
    const int L  = in_sizes[2] / (2 * CCH * CCH);

    float* xu = (float*)d_out;                 // [NU, C]
    float* xi = xu + (size_t)NU * CCH;         // [NI, C]  (final concat layout)

    float* agg_i = (float*)d_ws;                       // [NI, C]
    float* agg_u = agg_i + (size_t)NI * CCH;           // [NU, C]
    float* cnt_i = agg_u + (size_t)NU * CCH;           // [NI]
    float* cnt_u = cnt_i + NI;                         // [NU]
    const size_t zero_bytes = ((size_t)(NI + NU) * CCH + NI + NU) * sizeof(float);

    hipMemcpyAsync(xu, x_user, (size_t)NU * CCH * sizeof(float),
                   hipMemcpyDeviceToDevice, stream);
    hipMemcpyAsync(xi, x_item, (size_t)NI * CCH * sizeof(float),
                   hipMemcpyDeviceToDevice, stream);

    for (int l = 0; l < L; ++l) {
        hipMemsetAsync(d_ws, 0, zero_bytes, stream);

        const size_t w0  = ((size_t)l * 2 + 0) * CCH * CCH;  // conv params type 0
        const size_t w1  = ((size_t)l * 2 + 1) * CCH * CCH;  // conv params type 1
        const size_t b0  = ((size_t)l * 2 + 0) * CCH;
        const size_t b1  = ((size_t)l * 2 + 1) * CCH;
        const size_t lw0 = ((size_t)l * 2 + 0) * 2 * CCH * CCH;
        const size_t lw1 = ((size_t)l * 2 + 1) * 2 * CCH * CCH;

        // edge type 0: user -> item (src feats = xu, dst feats = xi)
        edge_conv_kernel<<<(E0 + EPB - 1) / EPB, TPB, 0, stream>>>(
            xu, xi, ei_ui, E0,
            pw1 + w0, pb1 + b0, pw2 + w0, pb2 + b0,
            msg_g + b0, msg_b + b0, agg_i, cnt_i);

        // edge type 1: item -> user (src feats = xi, dst feats = xu)
        edge_conv_kernel<<<(E1 + EPB - 1) / EPB, TPB, 0, stream>>>(
            xi, xu, ei_iu, E1,
            pw1 + w1, pb1 + b1, pw2 + w1, pb2 + b1,
            msg_g + b1, msg_b + b1, agg_u, cnt_u);

        // item update: conv/lin params [l,0], node-LN params [l,1]
        node_update_kernel<<<(NI + EPB - 1) / EPB, TPB, 0, stream>>>(
            xi, agg_i, cnt_i, lin_w + lw0, lin_b + b0,
            node_g + b1, node_b + b1, NI);

        // user update: conv/lin params [l,1], node-LN params [l,0]
        node_update_kernel<<<(NU + EPB - 1) / EPB, TPB, 0, stream>>>(
            xu, agg_u, cnt_u, lin_w + lw1, lin_b + b1,
            node_g + b0, node_b + b0, NU);
    }
}

// Round 3
// 2004.591 us; speedup vs baseline: 3.0508x; 3.0508x over previous
//
#include <hip/hip_runtime.h>
#include <cstddef>
#include <cstdint>

#define CCH 256

typedef unsigned short ushort_t;
typedef short bf16x8 __attribute__((ext_vector_type(8)));
typedef float f32x4 __attribute__((ext_vector_type(4)));

__device__ __forceinline__ ushort_t f2bf(float f) {
    unsigned u = __float_as_uint(f);
    u = u + 0x7FFFu + ((u >> 16) & 1u);   // round-to-nearest-even
    return (ushort_t)(u >> 16);
}
__device__ __forceinline__ float bf2f(ushort_t h) {
    return __uint_as_float(((unsigned)h) << 16);
}

__device__ __forceinline__ void gload16(const void* g, void* l) {
    __builtin_amdgcn_global_load_lds((const __attribute__((address_space(1))) unsigned*)g,
                                     (__attribute__((address_space(3))) unsigned*)l, 16, 0, 0);
}

// ---------------------------------------------------------------------------
// GEMM: out[M,256] = epilogue( A[M,K] @ B[K,256] + bias )
//   A is bf16, supplied as A0[M,256] (k<256) and A1[M,256] (k>=256, K=512 case)
//   BT is the transposed weight, bf16 [256][K]
//   EPI 0: relu(.+bias) -> bf16      (MLP layer 1)
//   EPI 1: (.+bias)     -> bf16      (MLP layer 2 -> P)
//   EPI 2: relu(LN(.+bias)*g+b) -> f32 + bf16  (node update)
// 512 threads = 8 waves; wave w owns output rows [w*16, w*16+16); BN=256 full.
// mfma_f32_16x16x32_bf16; A frag: lane row=l&15, k=(l>>4)*8..+8;
// C/D: col=lane&15, row=(lane>>4)*4+reg  (m89/m91-verified mapping).
// ---------------------------------------------------------------------------
template<int EPI>
__global__ __launch_bounds__(512)
void gemm_kernel(const ushort_t* __restrict__ A0, const ushort_t* __restrict__ A1,
                 int M, int K,
                 const ushort_t* __restrict__ BT,
                 const float* __restrict__ bias,
                 const float* __restrict__ lng, const float* __restrict__ lnb,
                 float* __restrict__ outF, ushort_t* __restrict__ outB)
{
    __shared__ ushort_t As[128 * 32];   // [row][k] 8 KB
    __shared__ ushort_t Bs[256 * 32];   // [col][k] 16 KB
    const int tid = threadIdx.x;
    const int w  = tid >> 6, l = tid & 63;
    const int ln = l & 15,  kh = l >> 4;
    const int m0 = blockIdx.x * 128;

    // staging: A tile rows m0..m0+127 (64B rows, 4x16B slots); wave w -> LDS [w*1KB,+1KB)
    const int  arow = w * 16 + (l >> 2);
    const long arg  = min((long)(m0 + arow), (long)(M - 1));
    const int  asl  = (l & 3) * 8;                 // element offset of 16B slot
    ushort_t* aDst = As + w * 512;
    // B tile: 256 rows of BT; wave w -> rows [w*32, +32) via two 1KB instrs
    const int  brow = w * 32 + (l >> 2);
    const int  bsl  = (l & 3) * 8;
    ushort_t* bDst0 = Bs + w * 1024;
    ushort_t* bDst1 = Bs + w * 1024 + 512;

    f32x4 acc[16];
    #pragma unroll
    for (int i = 0; i < 16; ++i) acc[i] = (f32x4)0.f;

    for (int kc = 0; kc < K; kc += 32) {
        const ushort_t* Asel = (kc < 256) ? A0 : A1;
        gload16(Asel + arg * 256 + (kc & 255) + asl, aDst);
        gload16(BT + (long)brow * K + kc + bsl, bDst0);
        gload16(BT + (long)(brow + 16) * K + kc + bsl, bDst1);
        __syncthreads();                            // staging visible (vmcnt drained)
        const bf16x8 af = *(const bf16x8*)&As[(w * 16 + ln) * 32 + kh * 8];
        #pragma unroll
        for (int fn = 0; fn < 16; ++fn) {
            const bf16x8 bf = *(const bf16x8*)&Bs[(fn * 16 + ln) * 32 + kh * 8];
            acc[fn] = __builtin_amdgcn_mfma_f32_16x16x32_bf16(af, bf, acc[fn], 0, 0, 0);
        }
        __syncthreads();                            // compute done before re-stage
    }

    if (EPI <= 1) {
        #pragma unroll
        for (int fn = 0; fn < 16; ++fn) {
            const int col = fn * 16 + ln;
            const float bv = bias[col];
            #pragma unroll
            for (int j = 0; j < 4; ++j) {
                const long gr = m0 + w * 16 + kh * 4 + j;
                float v = acc[fn][j] + bv;
                if (EPI == 0) v = fmaxf(v, 0.f);
                if (gr < M) outB[gr * 256 + col] = f2bf(v);
            }
        }
    } else {
        #pragma unroll
        for (int fn = 0; fn < 16; ++fn) {
            const float bv = bias[fn * 16 + ln];
            #pragma unroll
            for (int j = 0; j < 4; ++j) acc[fn][j] += bv;
        }
        #pragma unroll
        for (int j = 0; j < 4; ++j) {
            float s = 0.f, q = 0.f;
            #pragma unroll
            for (int fn = 0; fn < 16; ++fn) { const float v = acc[fn][j]; s += v; q += v * v; }
            #pragma unroll
            for (int m = 1; m < 16; m <<= 1) { s += __shfl_xor(s, m); q += __shfl_xor(q, m); }
            const float mu   = s * (1.f / 256.f);
            const float var  = q * (1.f / 256.f) - mu * mu;
            const float rstd = rsqrtf(var + 1e-5f);
            const long gr = m0 + w * 16 + kh * 4 + j;
            if (gr < M) {
                #pragma unroll
                for (int fn = 0; fn < 16; ++fn) {
                    const int col = fn * 16 + ln;
                    float y = (acc[fn][j] - mu) * rstd * lng[col] + lnb[col];
                    y = fmaxf(y, 0.f);
                    outF[gr * 256 + col] = y;
                    outB[gr * 256 + col] = f2bf(y);
                }
            }
        }
    }
}

// ---------------------------------------------------------------------------
// Edge kernel (memory-bound): r = x_src[src] - P[dst]; msg = LN(r)*mg+mb;
// agg[dst] += msg (atomics). One wave per edge-iteration; atomics issued with
// channel = lane + 64*j so each instruction's 64 lanes cover one contiguous
// 256B span (kills the 4x HBM write amplification seen in round 2).
// ---------------------------------------------------------------------------
__global__ __launch_bounds__(256)
void edge_kernel(const float* __restrict__ xsrc,
                 const ushort_t* __restrict__ P,
                 const int* __restrict__ ei, int E,
                 const float* __restrict__ mg, const float* __restrict__ mb,
                 float* __restrict__ agg)
{
    __shared__ float xp[4][256];
    const int tid = threadIdx.x;
    const int wv = tid >> 6, l = tid & 63;
    const int c4 = l * 4;
    const float4 mgv = *(const float4*)&mg[c4];
    const float4 mbv = *(const float4*)&mb[c4];
    const int base = (blockIdx.x * 4 + wv) * 8;
    for (int it = 0; it < 8; ++it) {
        const int e = base + it;          // wave-uniform
        const bool ok = (e < E);
        int d = 0;
        float r0 = 0.f, r1 = 0.f, r2 = 0.f, r3 = 0.f;
        if (ok) {
            const int s = ei[e];
            d = ei[E + e];
            const float4  xs = *(const float4*)&xsrc[(size_t)s * 256 + c4];
            const ushort4 pv = *(const ushort4*)&P[(size_t)d * 256 + c4];
            r0 = xs.x - bf2f(pv.x); r1 = xs.y - bf2f(pv.y);
            r2 = xs.z - bf2f(pv.z); r3 = xs.w - bf2f(pv.w);
        }
        float sm = r0 + r1 + r2 + r3;
        float sq = r0 * r0 + r1 * r1 + r2 * r2 + r3 * r3;
        #pragma unroll
        for (int m = 32; m >= 1; m >>= 1) { sm += __shfl_xor(sm, m); sq += __shfl_xor(sq, m); }
        const float mu   = sm * (1.f / 256.f);
        const float var  = sq * (1.f / 256.f) - mu * mu;
        const float rstd = rsqrtf(var + 1e-5f);
        float4 msg;
        msg.x = (r0 - mu) * rstd * mgv.x + mbv.x;
        msg.y = (r1 - mu) * rstd * mgv.y + mbv.y;
        msg.z = (r2 - mu) * rstd * mgv.z + mbv.z;
        msg.w = (r3 - mu) * rstd * mgv.w + mbv.w;
        *(float4*)&xp[wv][c4] = msg;
        __syncthreads();
        if (ok) {
            float* ap = agg + (size_t)d * 256;
            atomicAdd(ap + l,       xp[wv][l]);
            atomicAdd(ap + l + 64,  xp[wv][l + 64]);
            atomicAdd(ap + l + 128, xp[wv][l + 128]);
            atomicAdd(ap + l + 192, xp[wv][l + 192]);
        }
        __syncthreads();
    }
}

// fp32 -> bf16 elementwise (float4 granularity)
__global__ void conv_bf_kernel(const float* __restrict__ in, ushort_t* __restrict__ out, long n4)
{
    long i = (long)blockIdx.x * blockDim.x + threadIdx.x;
    const long stride = (long)gridDim.x * blockDim.x;
    for (; i < n4; i += stride) {
        const float4 v = ((const float4*)in)[i];
        ushort4 o; o.x = f2bf(v.x); o.y = f2bf(v.y); o.z = f2bf(v.z); o.w = f2bf(v.w);
        ((ushort4*)out)[i] = o;
    }
}

// agg/max(cnt,1) -> bf16
__global__ void div_bf_kernel(const float* __restrict__ agg, const float* __restrict__ cnt,
                              int N, ushort_t* __restrict__ out)
{
    long i = (long)blockIdx.x * blockDim.x + threadIdx.x;
    const long n4 = (long)N * 64;
    const long stride = (long)gridDim.x * blockDim.x;
    for (; i < n4; i += stride) {
        const float4 v = ((const float4*)agg)[i];
        const float inv = 1.f / fmaxf(cnt[i >> 6], 1.f);
        ushort4 o;
        o.x = f2bf(v.x * inv); o.y = f2bf(v.y * inv);
        o.z = f2bf(v.z * inv); o.w = f2bf(v.w * inv);
        ((ushort4*)out)[i] = o;
    }
}

// count edges per dst node
__global__ void count_kernel(const int* __restrict__ ei, int E, float* __restrict__ cnt)
{
    const int i = blockIdx.x * blockDim.x + threadIdx.x;
    if (i < E) atomicAdd(&cnt[ei[E + i]], 1.f);
}

// W [B][K][N] f32 -> WT [B][N][K] bf16 (tiled transpose)
__global__ void transpose_w_kernel(const float* __restrict__ in, ushort_t* __restrict__ out,
                                   int K, int N)
{
    __shared__ float t[32][33];
    const int b  = blockIdx.z;
    const int k0 = blockIdx.x * 32, n0 = blockIdx.y * 32;
    const int tx = threadIdx.x, ty = threadIdx.y;   // (32,8)
    const float* src = in + (size_t)b * K * N;
    #pragma unroll
    for (int j = 0; j < 32; j += 8) t[ty + j][tx] = src[(size_t)(k0 + ty + j) * N + n0 + tx];
    __syncthreads();
    ushort_t* dst = out + (size_t)b * N * K;
    #pragma unroll
    for (int j = 0; j < 32; j += 8) dst[(size_t)(n0 + ty + j) * K + k0 + tx] = f2bf(t[tx][ty + j]);
}

extern "C" void kernel_launch(void* const* d_in, const int* in_sizes, int n_in,
                              void* d_out, int out_size, void* d_ws, size_t ws_size,
                              hipStream_t stream)
{
    const float* x_user = (const float*)d_in[0];
    const float* x_item = (const float*)d_in[1];
    const float* pw1    = (const float*)d_in[2];
    const float* pb1    = (const float*)d_in[3];
    const float* pw2    = (const float*)d_in[4];
    const float* pb2    = (const float*)d_in[5];
    const float* msg_g  = (const float*)d_in[6];
    const float* msg_b  = (const float*)d_in[7];
    const float* lin_w  = (const float*)d_in[8];
    const float* lin_b  = (const float*)d_in[9];
    const float* node_g = (const float*)d_in[10];
    const float* node_b = (const float*)d_in[11];
    const int*   ei_ui  = (const int*)d_in[12];
    const int*   ei_iu  = (const int*)d_in[13];

    const int NU = in_sizes[0] / CCH;
    const int NI = in_sizes[1] / CCH;
    const int E0 = in_sizes[12] / 2;
    const int E1 = in_sizes[13] / 2;
    const int L  = in_sizes[2] / (2 * CCH * CCH);
    const long Nmax = (NU > NI) ? NU : NI;

    // ---- workspace layout ----
    float* agg_i = (float*)d_ws;                        // NI*256 f32
    float* agg_u = agg_i + (size_t)NI * CCH;            // NU*256 f32
    float* cnt_i = agg_u + (size_t)NU * CCH;            // NI
    float* cnt_u = cnt_i + NI;                          // NU
    ushort_t* Xu_bf = (ushort_t*)(cnt_u + NU);          // NU*256 bf16
    ushort_t* Xi_bf = Xu_bf + (size_t)NU * CCH;         // NI*256
    ushort_t* Hbf   = Xi_bf + (size_t)NI * CCH;         // Nmax*256 (scratch)
    ushort_t* Pbf   = Hbf + Nmax * CCH;                 // Nmax*256 (scratch)
    ushort_t* pw1T  = Pbf + Nmax * CCH;                 // L*2*256*256
    ushort_t* pw2T  = pw1T + (size_t)L * 2 * CCH * CCH;
    ushort_t* linT  = pw2T + (size_t)L * 2 * CCH * CCH; // L*2*256*512

    float* Xu_f = (float*)d_out;
    float* Xi_f = Xu_f + (size_t)NU * CCH;

    // ---- per-call prep ----
    hipMemsetAsync(cnt_i, 0, (size_t)(NI + NU) * sizeof(float), stream);
    count_kernel<<<(E0 + 255) / 256, 256, 0, stream>>>(ei_ui, E0, cnt_i);
    count_kernel<<<(E1 + 255) / 256, 256, 0, stream>>>(ei_iu, E1, cnt_u);
    conv_bf_kernel<<<2048, 256, 0, stream>>>(x_user, Xu_bf, (long)NU * 64);
    conv_bf_kernel<<<2048, 256, 0, stream>>>(x_item, Xi_bf, (long)NI * 64);
    {
        dim3 b(32, 8);
        transpose_w_kernel<<<dim3(8, 8, L * 2), b, 0, stream>>>(pw1, pw1T, 256, 256);
        transpose_w_kernel<<<dim3(8, 8, L * 2), b, 0, stream>>>(pw2, pw2T, 256, 256);
        transpose_w_kernel<<<dim3(16, 8, L * 2), b, 0, stream>>>(lin_w, linT, 512, 256);
    }

    const int gI = (NI + 127) / 128, gU = (NU + 127) / 128;

    for (int l = 0; l < L; ++l) {
        hipMemsetAsync(agg_i, 0, (size_t)(NI + NU) * CCH * sizeof(float), stream);

        const size_t pw0 = ((size_t)l * 2 + 0) * CCH * CCH;
        const size_t pw1o = ((size_t)l * 2 + 1) * CCH * CCH;
        const size_t b0  = ((size_t)l * 2 + 0) * CCH;
        const size_t b1  = ((size_t)l * 2 + 1) * CCH;
        const size_t lw0 = ((size_t)l * 2 + 0) * 2 * CCH * CCH;
        const size_t lw1 = ((size_t)l * 2 + 1) * 2 * CCH * CCH;

        const float* xu_cur = (l == 0) ? x_user : Xu_f;
        const float* xi_cur = (l == 0) ? x_item : Xi_f;

        // conv type 0 (user->item, dst=item): P = MLP(x_item) densely per node
        gemm_kernel<0><<<gI, 512, 0, stream>>>(Xi_bf, nullptr, NI, 256, pw1T + pw0,
                                               pb1 + b0, nullptr, nullptr, nullptr, Hbf);
        gemm_kernel<1><<<gI, 512, 0, stream>>>(Hbf, nullptr, NI, 256, pw2T + pw0,
                                               pb2 + b0, nullptr, nullptr, nullptr, Pbf);
        edge_kernel<<<(E0 + 31) / 32, 256, 0, stream>>>(xu_cur, Pbf, ei_ui, E0,
                                                        msg_g + b0, msg_b + b0, agg_i);

        // conv type 1 (item->user, dst=user)
        gemm_kernel<0><<<gU, 512, 0, stream>>>(Xu_bf, nullptr, NU, 256, pw1T + pw1o,
                                               pb1 + b1, nullptr, nullptr, nullptr, Hbf);
        gemm_kernel<1><<<gU, 512, 0, stream>>>(Hbf, nullptr, NU, 256, pw2T + pw1o,
                                               pb2 + b1, nullptr, nullptr, nullptr, Pbf);
        edge_kernel<<<(E1 + 31) / 32, 256, 0, stream>>>(xi_cur, Pbf, ei_iu, E1,
                                                        msg_g + b1, msg_b + b1, agg_u);

        // mean aggregation -> bf16 (reuse H/P scratch, both dead now)
        div_bf_kernel<<<2048, 256, 0, stream>>>(agg_i, cnt_i, NI, Hbf);
        div_bf_kernel<<<2048, 256, 0, stream>>>(agg_u, cnt_u, NU, Pbf);

        // node updates: concat(x, agg) @ LW -> LN -> relu  (writes f32 out + bf16)
        // item update: lin params [l,0], node-LN params [l,1]
        gemm_kernel<2><<<gI, 512, 0, stream>>>(Xi_bf, Hbf, NI, 512, linT + lw0,
                                               lin_b + b0, node_g + b1, node_b + b1,
                                               Xi_f, Xi_bf);
        // user update: lin params [l,1], node-LN params [l,0]
        gemm_kernel<2><<<gU, 512, 0, stream>>>(Xu_bf, Pbf, NU, 512, linT + lw1,
                                               lin_b + b1, node_g + b0, node_b + b0,
                                               Xu_f, Xu_bf);
    }
}

// Round 5
// 1701.604 us; speedup vs baseline: 3.5941x; 1.1781x over previous
//
#include <hip/hip_runtime.h>
#include <hip/hip_fp16.h>
#include <cstddef>

#define CCH 256

typedef unsigned short ushort_t;
typedef short bf16x8 __attribute__((ext_vector_type(8)));
typedef _Float16 f16x8 __attribute__((ext_vector_type(8)));
typedef _Float16 f16x2 __attribute__((ext_vector_type(2)));
typedef float f32x4 __attribute__((ext_vector_type(4)));

__device__ __forceinline__ ushort_t f2bf(float f) {
    unsigned u = __float_as_uint(f);
    u = u + 0x7FFFu + ((u >> 16) & 1u);
    return (ushort_t)(u >> 16);
}
__device__ __forceinline__ float bf2f(ushort_t h) {
    return __uint_as_float(((unsigned)h) << 16);
}
__device__ __forceinline__ ushort_t f2h(float f) {
    _Float16 h = (_Float16)f;
    return __builtin_bit_cast(unsigned short, h);
}

__device__ __forceinline__ void gload16(const void* g, void* l) {
    __builtin_amdgcn_global_load_lds((const __attribute__((address_space(1))) unsigned*)g,
                                     (__attribute__((address_space(3))) unsigned*)l, 16, 0, 0);
}

__device__ __forceinline__ void atomic_add_f16x2(void* p, float a, float b) {
    f16x2 v; v[0] = (_Float16)a; v[1] = (_Float16)b;
#if __has_builtin(__builtin_amdgcn_global_atomic_fadd_v2f16)
    (void)__builtin_amdgcn_global_atomic_fadd_v2f16(
        (__attribute__((address_space(1))) f16x2*)p, v);
#else
    (void)unsafeAtomicAdd((__half2*)p, *(__half2*)&v);
#endif
}

// ---------------------------------------------------------------------------
// GEMM: out[M,256] = epilogue( A[M,K] @ B[K,256] + bias ),  BT = B^T [256][K].
// 256 thr = 4 waves, wave tile 64x64 (4 A-frags + 4 B-frags : 16 MFMA).
// EPI 0: relu(.+bias)->bf16   tile 128x128, grid (M/128, 2)
// EPI 1: (.+bias)->bf16       tile 128x128
// EPI 2: relu(LN(.+bias)*g+b)->f32+bf16, tile 64x256 (LN block-local),
//        K=512: k<256 bf16 A0/BT-lo, k>=256 f16 A1/BT-hi (mfma f16).
// LDS rows are 32 x 16-bit elems (64B). XOR slot swizzle (T2): LDS[r][s]
// holds global slot s ^ ((r>>1)&3)  -> applied on the *global* source addr
// (gload_lds writes linearly), read back with sw = kh ^ ((ln>>1)&3).
// Uniform 2-way bank aliasing = free (m136).
// ---------------------------------------------------------------------------
template<int EPI>
__global__ __launch_bounds__(256)
void gemm_kernel(const ushort_t* __restrict__ A0, const ushort_t* __restrict__ A1,
                 int M, int K,
                 const ushort_t* __restrict__ BT,
                 const float* __restrict__ bias,
                 const float* __restrict__ lng, const float* __restrict__ lnb,
                 float* __restrict__ outF, ushort_t* __restrict__ outB)
{
    constexpr int BM = (EPI == 2) ? 64 : 128;
    constexpr int BN = (EPI == 2) ? 256 : 128;
    __shared__ __align__(16) ushort_t As[BM * 32];
    __shared__ __align__(16) ushort_t Bs[BN * 32];
    __shared__ float lnp[(EPI == 2) ? 64 : 1][8];

    const int tid = threadIdx.x;
    const int w = tid >> 6, l = tid & 63;
    const int ln = l & 15, kh = l >> 4;
    const int wr = (EPI == 2) ? 0 : (w >> 1);
    const int wc = (EPI == 2) ? w : (w & 1);
    const int m0 = blockIdx.x * BM;
    const int n0 = (EPI == 2) ? 0 : (blockIdx.y * BN);

    const int gsl = ((l & 3) ^ ((l >> 3) & 3)) << 3;   // staging: global slot (elems)
    const int sw8 = (kh ^ ((ln >> 1) & 3)) << 3;       // read: swizzled slot (elems)

    f32x4 acc[4][4];
    #pragma unroll
    for (int m = 0; m < 4; ++m)
        #pragma unroll
        for (int n = 0; n < 4; ++n) acc[m][n] = (f32x4)0.f;

    for (int kc = 0; kc < K; kc += 32) {
        const ushort_t* Ap = A0;
        if constexpr (EPI == 2) { if (kc >= 256) Ap = A1; }
        #pragma unroll
        for (int i = 0; i < BM / 64; ++i) {
            const int rl = w * (BM / 4) + i * 16 + (l >> 2);
            long gr = m0 + rl; if (gr > M - 1) gr = M - 1;
            gload16(Ap + gr * 256 + (kc & 255) + gsl,
                    (void*)(As + w * (BM / 4) * 32 + i * 512));
        }
        #pragma unroll
        for (int i = 0; i < BN / 64; ++i) {
            const int rl = w * (BN / 4) + i * 16 + (l >> 2);
            gload16(BT + (long)(n0 + rl) * K + kc + gsl,
                    (void*)(Bs + w * (BN / 4) * 32 + i * 512));
        }
        __syncthreads();   // vmcnt drained by compiler before barrier

        bf16x8 afr[4], bfr[4];
        #pragma unroll
        for (int m = 0; m < 4; ++m)
            afr[m] = *(const bf16x8*)&As[(wr * 64 + m * 16 + ln) * 32 + sw8];
        #pragma unroll
        for (int n = 0; n < 4; ++n)
            bfr[n] = *(const bf16x8*)&Bs[(wc * 64 + n * 16 + ln) * 32 + sw8];

        bool use_f16 = false;
        if constexpr (EPI == 2) use_f16 = (kc >= 256);
        if (use_f16) {
            #pragma unroll
            for (int m = 0; m < 4; ++m)
                #pragma unroll
                for (int n = 0; n < 4; ++n)
                    acc[m][n] = __builtin_amdgcn_mfma_f32_16x16x32_f16(
                        __builtin_bit_cast(f16x8, afr[m]),
                        __builtin_bit_cast(f16x8, bfr[n]), acc[m][n], 0, 0, 0);
        } else {
            #pragma unroll
            for (int m = 0; m < 4; ++m)
                #pragma unroll
                for (int n = 0; n < 4; ++n)
                    acc[m][n] = __builtin_amdgcn_mfma_f32_16x16x32_bf16(
                        afr[m], bfr[n], acc[m][n], 0, 0, 0);
        }
        __syncthreads();   // protect LDS before re-stage
    }

    if constexpr (EPI <= 1) {
        #pragma unroll
        for (int n = 0; n < 4; ++n) {
            const int col = n0 + wc * 64 + n * 16 + ln;
            const float bv = bias[col];
            #pragma unroll
            for (int m = 0; m < 4; ++m)
                #pragma unroll
                for (int j = 0; j < 4; ++j) {
                    const long gr = m0 + wr * 64 + m * 16 + kh * 4 + j;
                    float v = acc[m][n][j] + bv;
                    if (EPI == 0) v = fmaxf(v, 0.f);
                    if (gr < M) outB[gr * 256 + col] = f2bf(v);
                }
        }
    } else {
        float gv[4], bv2[4];
        #pragma unroll
        for (int n = 0; n < 4; ++n) {
            const int col = wc * 64 + n * 16 + ln;
            const float bv = bias[col];
            gv[n] = lng[col]; bv2[n] = lnb[col];
            #pragma unroll
            for (int m = 0; m < 4; ++m)
                #pragma unroll
                for (int j = 0; j < 4; ++j) acc[m][n][j] += bv;
        }
        // per-row partial (this wave's 64 cols) -> LDS
        #pragma unroll
        for (int m = 0; m < 4; ++m)
            #pragma unroll
            for (int j = 0; j < 4; ++j) {
                float s = 0.f, q = 0.f;
                #pragma unroll
                for (int n = 0; n < 4; ++n) { const float v = acc[m][n][j]; s += v; q += v * v; }
                #pragma unroll
                for (int mm = 1; mm < 16; mm <<= 1) { s += __shfl_xor(s, mm); q += __shfl_xor(q, mm); }
                if (ln == 0) {
                    const int r = m * 16 + kh * 4 + j;
                    lnp[r][wc] = s; lnp[r][4 + wc] = q;
                }
            }
        __syncthreads();
        #pragma unroll
        for (int m = 0; m < 4; ++m)
            #pragma unroll
            for (int j = 0; j < 4; ++j) {
                const int r = m * 16 + kh * 4 + j;
                const float4 s4 = *(const float4*)&lnp[r][0];
                const float4 q4 = *(const float4*)&lnp[r][4];
                const float s = s4.x + s4.y + s4.z + s4.w;
                const float q = q4.x + q4.y + q4.z + q4.w;
                const float mu = s * (1.f / 256.f);
                const float var = q * (1.f / 256.f) - mu * mu;
                const float rstd = rsqrtf(var + 1e-5f);
                const long gr = m0 + r;
                if (gr < M) {
                    #pragma unroll
                    for (int n = 0; n < 4; ++n) {
                        const int col = wc * 64 + n * 16 + ln;
                        float y = (acc[m][n][j] - mu) * rstd * gv[n] + bv2[n];
                        y = fmaxf(y, 0.f);
                        outF[gr * 256 + col] = y;
                        outB[gr * 256 + col] = f2bf(y);
                    }
                }
            }
    }
}

// ---------------------------------------------------------------------------
// Edge kernel: one edge per wave, no loop / no barriers.
// Lane l owns channels {2l, 2l+1, 128+2l, 129+2l} so the two packed-f16
// atomics per lane are contiguous 256B spans per instruction.
// msg = LN(x_src[s]-P[d])*g+b, scaled by 1/max(cnt[d],1) (mean folded in).
// ---------------------------------------------------------------------------
__global__ __launch_bounds__(256)
void edge_kernel(const ushort_t* __restrict__ xsrc,
                 const ushort_t* __restrict__ P,
                 const int* __restrict__ ei, int E,
                 const float* __restrict__ mg, const float* __restrict__ mb,
                 const float* __restrict__ cnt,
                 unsigned* __restrict__ agg)
{
    const int l = threadIdx.x & 63;
    const long e = (long)blockIdx.x * 4 + (threadIdx.x >> 6);
    if (e >= E) return;
    const int s = ei[e];
    const int d = ei[E + e];
    const float inv = 1.f / fmaxf(cnt[d], 1.f);
    const unsigned xl = *(const unsigned*)&xsrc[(size_t)s * 256 + 2 * l];
    const unsigned xh = *(const unsigned*)&xsrc[(size_t)s * 256 + 128 + 2 * l];
    const unsigned pl = *(const unsigned*)&P[(size_t)d * 256 + 2 * l];
    const unsigned ph = *(const unsigned*)&P[(size_t)d * 256 + 128 + 2 * l];
    const float r0 = bf2f((ushort_t)(xl & 0xffff)) - bf2f((ushort_t)(pl & 0xffff));
    const float r1 = bf2f((ushort_t)(xl >> 16))    - bf2f((ushort_t)(pl >> 16));
    const float r2 = bf2f((ushort_t)(xh & 0xffff)) - bf2f((ushort_t)(ph & 0xffff));
    const float r3 = bf2f((ushort_t)(xh >> 16))    - bf2f((ushort_t)(ph >> 16));
    float sm = r0 + r1 + r2 + r3;
    float sq = r0 * r0 + r1 * r1 + r2 * r2 + r3 * r3;
    #pragma unroll
    for (int m = 32; m >= 1; m >>= 1) { sm += __shfl_xor(sm, m); sq += __shfl_xor(sq, m); }
    const float mu = sm * (1.f / 256.f);
    const float var = sq * (1.f / 256.f) - mu * mu;
    const float rstd = rsqrtf(var + 1e-5f);
    const float2 g_lo = *(const float2*)&mg[2 * l];
    const float2 g_hi = *(const float2*)&mg[128 + 2 * l];
    const float2 b_lo = *(const float2*)&mb[2 * l];
    const float2 b_hi = *(const float2*)&mb[128 + 2 * l];
    const float m0v = ((r0 - mu) * rstd * g_lo.x + b_lo.x) * inv;
    const float m1v = ((r1 - mu) * rstd * g_lo.y + b_lo.y) * inv;
    const float m2v = ((r2 - mu) * rstd * g_hi.x + b_hi.x) * inv;
    const float m3v = ((r3 - mu) * rstd * g_hi.y + b_hi.y) * inv;
    unsigned* base = agg + (size_t)d * 128;
    atomic_add_f16x2((void*)(base + l), m0v, m1v);
    atomic_add_f16x2((void*)(base + 64 + l), m2v, m3v);
}

// fp32 -> bf16 elementwise (float4 granularity)
__global__ void conv_bf_kernel(const float* __restrict__ in, ushort_t* __restrict__ out, long n4)
{
    long i = (long)blockIdx.x * blockDim.x + threadIdx.x;
    const long stride = (long)gridDim.x * blockDim.x;
    for (; i < n4; i += stride) {
        const float4 v = ((const float4*)in)[i];
        ushort4 o; o.x = f2bf(v.x); o.y = f2bf(v.y); o.z = f2bf(v.z); o.w = f2bf(v.w);
        ((ushort4*)out)[i] = o;
    }
}

__global__ void count_kernel(const int* __restrict__ ei, int E, float* __restrict__ cnt)
{
    const int i = blockIdx.x * blockDim.x + threadIdx.x;
    if (i < E) atomicAdd(&cnt[ei[E + i]], 1.f);
}

// W [B][K][N] f32 -> WT [B][N][K] 16-bit (bf16, or f16 for k >= f16_from)
__global__ void transpose_w_kernel(const float* __restrict__ in, ushort_t* __restrict__ out,
                                   int K, int N, int f16_from)
{
    __shared__ float t[32][33];
    const int b = blockIdx.z;
    const int k0 = blockIdx.x * 32, n0 = blockIdx.y * 32;
    const int tx = threadIdx.x, ty = threadIdx.y;   // (32,8)
    const float* src = in + (size_t)b * K * N;
    #pragma unroll
    for (int j = 0; j < 32; j += 8) t[ty + j][tx] = src[(size_t)(k0 + ty + j) * N + n0 + tx];
    __syncthreads();
    ushort_t* dst = out + (size_t)b * N * K;
    #pragma unroll
    for (int j = 0; j < 32; j += 8) {
        const float v = t[tx][ty + j];
        const int kk = k0 + tx;
        dst[(size_t)(n0 + ty + j) * K + kk] = (kk >= f16_from) ? f2h(v) : f2bf(v);
    }
}

extern "C" void kernel_launch(void* const* d_in, const int* in_sizes, int n_in,
                              void* d_out, int out_size, void* d_ws, size_t ws_size,
                              hipStream_t stream)
{
    const float* x_user = (const float*)d_in[0];
    const float* x_item = (const float*)d_in[1];
    const float* pw1    = (const float*)d_in[2];
    const float* pb1    = (const float*)d_in[3];
    const float* pw2    = (const float*)d_in[4];
    const float* pb2    = (const float*)d_in[5];
    const float* msg_g  = (const float*)d_in[6];
    const float* msg_b  = (const float*)d_in[7];
    const float* lin_w  = (const float*)d_in[8];
    const float* lin_b  = (const float*)d_in[9];
    const float* node_g = (const float*)d_in[10];
    const float* node_b = (const float*)d_in[11];
    const int*   ei_ui  = (const int*)d_in[12];
    const int*   ei_iu  = (const int*)d_in[13];

    const int NU = in_sizes[0] / CCH;
    const int NI = in_sizes[1] / CCH;
    const int E0 = in_sizes[12] / 2;
    const int E1 = in_sizes[13] / 2;
    const int L  = in_sizes[2] / (2 * CCH * CCH);
    const long Nmax = (NU > NI) ? NU : NI;

    // ---- workspace layout (16-bit unless noted) ----
    ushort_t* base  = (ushort_t*)d_ws;
    ushort_t* agg_i = base;                             // NI*256 f16
    ushort_t* agg_u = agg_i + (size_t)NI * CCH;         // NU*256 f16
    ushort_t* Xu_bf = agg_u + (size_t)NU * CCH;         // NU*256 bf16
    ushort_t* Xi_bf = Xu_bf + (size_t)NU * CCH;         // NI*256 bf16
    ushort_t* Hbf   = Xi_bf + (size_t)NI * CCH;         // Nmax*256 scratch
    ushort_t* Pbf   = Hbf + Nmax * CCH;                 // Nmax*256 scratch
    ushort_t* pw1T  = Pbf + Nmax * CCH;                 // L*2*256*256
    ushort_t* pw2T  = pw1T + (size_t)L * 2 * CCH * CCH;
    ushort_t* linT  = pw2T + (size_t)L * 2 * CCH * CCH; // L*2*256*512
    float*    cnt_i = (float*)(linT + (size_t)L * 2 * CCH * 2 * CCH);  // NI f32
    float*    cnt_u = cnt_i + NI;                       // NU f32

    float* Xu_f = (float*)d_out;
    float* Xi_f = Xu_f + (size_t)NU * CCH;

    // ---- per-call prep ----
    hipMemsetAsync(cnt_i, 0, (size_t)(NI + NU) * sizeof(float), stream);
    count_kernel<<<(E0 + 255) / 256, 256, 0, stream>>>(ei_ui, E0, cnt_i);
    count_kernel<<<(E1 + 255) / 256, 256, 0, stream>>>(ei_iu, E1, cnt_u);
    conv_bf_kernel<<<2048, 256, 0, stream>>>(x_user, Xu_bf, (long)NU * 64);
    conv_bf_kernel<<<2048, 256, 0, stream>>>(x_item, Xi_bf, (long)NI * 64);
    {
        dim3 b(32, 8);
        transpose_w_kernel<<<dim3(8, 8, L * 2), b, 0, stream>>>(pw1, pw1T, 256, 256, 1 << 30);
        transpose_w_kernel<<<dim3(8, 8, L * 2), b, 0, stream>>>(pw2, pw2T, 256, 256, 1 << 30);
        transpose_w_kernel<<<dim3(16, 8, L * 2), b, 0, stream>>>(lin_w, linT, 512, 256, 256);
    }

    const dim3 gS_I((NI + 127) / 128, 2), gS_U((NU + 127) / 128, 2);
    const int  gL_I = (NI + 63) / 64,     gL_U = (NU + 63) / 64;

    for (int l = 0; l < L; ++l) {
        hipMemsetAsync(agg_i, 0, (size_t)(NI + NU) * CCH * sizeof(ushort_t), stream);

        const size_t w0  = ((size_t)l * 2 + 0) * CCH * CCH;
        const size_t w1  = ((size_t)l * 2 + 1) * CCH * CCH;
        const size_t b0  = ((size_t)l * 2 + 0) * CCH;
        const size_t b1  = ((size_t)l * 2 + 1) * CCH;
        const size_t lw0 = ((size_t)l * 2 + 0) * 2 * CCH * CCH;
        const size_t lw1 = ((size_t)l * 2 + 1) * 2 * CCH * CCH;

        // conv type 0 (user->item, dst=item): P = MLP(x_item) per node
        gemm_kernel<0><<<gS_I, 256, 0, stream>>>(Xi_bf, nullptr, NI, 256, pw1T + w0,
                                                 pb1 + b0, nullptr, nullptr, nullptr, Hbf);
        gemm_kernel<1><<<gS_I, 256, 0, stream>>>(Hbf, nullptr, NI, 256, pw2T + w0,
                                                 pb2 + b0, nullptr, nullptr, nullptr, Pbf);
        edge_kernel<<<(E0 + 3) / 4, 256, 0, stream>>>(Xu_bf, Pbf, ei_ui, E0,
                                                      msg_g + b0, msg_b + b0, cnt_i,
                                                      (unsigned*)agg_i);

        // conv type 1 (item->user, dst=user)
        gemm_kernel<0><<<gS_U, 256, 0, stream>>>(Xu_bf, nullptr, NU, 256, pw1T + w1,
                                                 pb1 + b1, nullptr, nullptr, nullptr, Hbf);
        gemm_kernel<1><<<gS_U, 256, 0, stream>>>(Hbf, nullptr, NU, 256, pw2T + w1,
                                                 pb2 + b1, nullptr, nullptr, nullptr, Pbf);
        edge_kernel<<<(E1 + 3) / 4, 256, 0, stream>>>(Xi_bf, Pbf, ei_iu, E1,
                                                      msg_g + b1, msg_b + b1, cnt_u,
                                                      (unsigned*)agg_u);

        // node updates: concat(x_bf16, agg_f16) @ LW -> LN -> relu
        // item: lin params [l,0], node-LN params [l,1]
        gemm_kernel<2><<<gL_I, 256, 0, stream>>>(Xi_bf, agg_i, NI, 512, linT + lw0,
                                                 lin_b + b0, node_g + b1, node_b + b1,
                                                 Xi_f, Xi_bf);
        // user: lin params [l,1], node-LN params [l,0]
        gemm_kernel<2><<<gL_U, 256, 0, stream>>>(Xu_bf, agg_u, NU, 512, linT + lw1,
                                                 lin_b + b1, node_g + b0, node_b + b0,
                                                 Xu_f, Xu_bf);
    }
}